// Round 1
// baseline (258.016 us; speedup 1.0000x reference)
//
#include <hip/hip_runtime.h>
#include <hip/hip_bf16.h>

// CQRN fused kernel for MI355X (gfx950)
// S=256 B=16 C=64 N=128 H=64; conv(1x9, pad4) -> ELU/sig gates -> ForgetMult -> O*C
//
// Strategy:
//  - prep kernel: W (192,64,9) fp32 -> bf16 A-fragments in d_ws, tau-major K=576
//  - main kernel: 256 blocks = (b, h-tile32, n-tile32, s-chunk2), 4 waves
//    per batch of SB=8 steps: GEMM (mfma 16x16x32 bf16) -> in-lane recurrence
//    chunk1 warms up 24 steps from c=0 (recurrence contracts; error ~2^-31)

typedef __attribute__((ext_vector_type(8))) short s8v;
typedef __attribute__((ext_vector_type(4))) float f4v;

#define HOUT_ELEMS (256*16*64*128)

__device__ __forceinline__ unsigned short f2bf(float x) {
    unsigned u = __float_as_uint(x);
    u += 0x7fffu + ((u >> 16) & 1u);   // round-to-nearest-even
    return (unsigned short)(u >> 16);
}

// ---------------- pre-pass: W -> A-fragment layout (bf16) ----------------
// Af[gt][ks][lane][j] : gt in [0,12) 16-row oc tiles; ks in [0,18) K-steps of 32
// oc = gt*16 + (lane&15); k = ks*32 + (lane>>4)*8 + j; tau = k>>6; c = k&63
// W global layout: W[oc][c][tau]  (oc stride 576, c stride 9, tau stride 1)
__global__ void prep_w_kernel(const float* __restrict__ W, short* __restrict__ Wf) {
    int t = blockIdx.x * 256 + threadIdx.x;
    if (t >= 12 * 18 * 64) return;
    int lane = t & 63;
    int ks = (t >> 6) % 18;
    int gt = (t >> 6) / 18;
    int oc = gt * 16 + (lane & 15);
    s8v v;
#pragma unroll
    for (int j = 0; j < 8; ++j) {
        int k = ks * 32 + ((lane >> 4) << 3) + j;
        int tau = k >> 6;
        int cc = k & 63;
        v[j] = (short)f2bf(W[(oc * 64 + cc) * 9 + tau]);
    }
    *(s8v*)(Wf + (size_t)t * 8) = v;
}

// ---------------- main fused kernel ----------------
__global__ __launch_bounds__(256, 1)
void cqrn_main_kernel(const float* __restrict__ X, const float* __restrict__ hid,
                      const float* __restrict__ bias, const short* __restrict__ Wf,
                      float* __restrict__ out)
{
    // X tile: [s(8)][nl(40)][c(64)] bf16, XOR-swizzled at 16B granularity within
    // each 128B row: byte_in_row = (2c) ^ ((nl&7)<<4). 40,960 B.
    __shared__ short Xt[8 * 40 * 64];

    const int tid  = threadIdx.x;
    const int lane = tid & 63;
    const int w    = tid >> 6;
    const int hs   = w >> 1;          // h-sub (16 rows)
    const int ns   = w & 1;           // n-sub (16 cols)

    const int bid = blockIdx.x;
    const int b   = bid & 15;
    const int h0  = ((bid >> 4) & 1) * 32;
    const int n0  = ((bid >> 5) & 3) * 32;
    const int sc  = (bid >> 7) & 1;

    const int s_begin = sc ? 120 : 0;    // chunk1: 24 warmup steps
    const int nb      = sc ? 17 : 18;    // batches of 8 steps
    const int s_store = sc ? 144 : 0;    // chunk0 stores [0,144), chunk1 [144,256)

    // D fragment layout (16x16): col = lane&15, row = (lane>>4)*4 + reg
    const int drow  = (lane >> 4) << 2;
    const int dcol  = lane & 15;
    const int hbase = h0 + 16 * hs + drow;   // + r
    const int nidx  = n0 + 16 * ns + dcol;

    // biases for this lane's 4 rows, per gate (folded into acc init)
    float bz[4], bf_[4], bo[4];
#pragma unroll
    for (int r = 0; r < 4; ++r) {
        bz[r]  = bias[hbase + r];
        bf_[r] = bias[64  + hbase + r];
        bo[r]  = bias[128 + hbase + r];
    }

    // recurrence state
    float c[4];
#pragma unroll
    for (int r = 0; r < 4; ++r)
        c[r] = sc ? 0.f : hid[(size_t)(b * 64 + hbase + r) * 128 + nidx];

    // A-fragment base pointers (one per gate); gate g rows = g*64 + h0 + 16*hs
    const short* Ap0 = Wf + (size_t)(((0 * 4 + (h0 >> 4) + hs) * 18) * 64 + lane) * 8;
    const short* Ap1 = Wf + (size_t)(((1 * 4 + (h0 >> 4) + hs) * 18) * 64 + lane) * 8;
    const short* Ap2 = Wf + (size_t)(((2 * 4 + (h0 >> 4) + hs) * 18) * 64 + lane) * 8;

    // staging mapping: lane -> channel c, wave -> s-pair {2w, 2w+1}
    const int scc = tid & 63;
    const int ssp = (tid >> 6) * 2;

    // ---- prologue: stage batch 0 ----
#pragma unroll
    for (int ss2 = 0; ss2 < 2; ++ss2) {
        int ss = ssp + ss2;
        const float* src = X + (size_t)(((s_begin + ss) * 16 + b) * 64 + scc) * 128;
#pragma unroll
        for (int q = 0; q < 10; ++q) {
            int n = n0 - 4 + q * 4;
            f4v v = 0.f;
            if (n >= 0 && n < 128) v = *(const f4v*)(src + n);
#pragma unroll
            for (int e = 0; e < 4; ++e) {
                int nl = q * 4 + e;
                int byteoff = ((ss * 40 + nl) << 7) + ((scc * 2) ^ ((nl & 7) << 4));
                *(short*)((char*)Xt + byteoff) = (short)f2bf(v[e]);
            }
        }
    }
    __syncthreads();

    for (int bt = 0; bt < nb; ++bt) {
        const int sbase = s_begin + bt * 8;

        // accumulators (3 gates x 8 steps), init = bias
        f4v acc[3][8];
#pragma unroll
        for (int s = 0; s < 8; ++s) {
            acc[0][s] = (f4v){bz[0], bz[1], bz[2], bz[3]};
            acc[1][s] = (f4v){bf_[0], bf_[1], bf_[2], bf_[3]};
            acc[2][s] = (f4v){bo[0], bo[1], bo[2], bo[3]};
        }

        // ---- GEMM: K = 576 in 18 steps of 32 ----
        for (int ks = 0; ks < 18; ++ks) {
            s8v a0 = *(const s8v*)(Ap0 + (size_t)ks * 512);
            s8v a1 = *(const s8v*)(Ap1 + (size_t)ks * 512);
            s8v a2 = *(const s8v*)(Ap2 + (size_t)ks * 512);
            const int tau = ks >> 1;
            const int nl = dcol + 16 * ns + tau;
            const int cbyte = ((((ks & 1) << 6) + ((lane >> 4) << 4)) ^ ((nl & 7) << 4));
            const char* base = (const char*)Xt + (nl << 7) + cbyte;
#pragma unroll
            for (int s = 0; s < 8; ++s) {
                s8v bb = *(const s8v*)(base + s * 5120);
                acc[0][s] = __builtin_amdgcn_mfma_f32_16x16x32_bf16(a0, bb, acc[0][s], 0, 0, 0);
                acc[1][s] = __builtin_amdgcn_mfma_f32_16x16x32_bf16(a1, bb, acc[1][s], 0, 0, 0);
                acc[2][s] = __builtin_amdgcn_mfma_f32_16x16x32_bf16(a2, bb, acc[2][s], 0, 0, 0);
            }
        }
        __syncthreads();   // all waves done reading Xt

        // ---- issue next batch's global loads early (T14) ----
        const bool do_stage = (bt + 1 < nb);
        f4v stg[2][10];
        if (do_stage) {
#pragma unroll
            for (int ss2 = 0; ss2 < 2; ++ss2) {
                int ss = ssp + ss2;
                const float* src = X + (size_t)(((sbase + 8 + ss) * 16 + b) * 64 + scc) * 128;
#pragma unroll
                for (int q = 0; q < 10; ++q) {
                    int n = n0 - 4 + q * 4;
                    f4v v = 0.f;
                    if (n >= 0 && n < 128) v = *(const f4v*)(src + n);
                    stg[ss2][q] = v;
                }
            }
        }

        // ---- activations + in-lane recurrence + Hout stores ----
#pragma unroll
        for (int s = 0; s < 8; ++s) {
            const int sg = sbase + s;
            const bool st = (sg >= s_store);
#pragma unroll
            for (int r = 0; r < 4; ++r) {
                float z = acc[0][s][r];
                float f = acc[1][s][r];
                float o = acc[2][s][r];
                z = (z > 0.f) ? z : (__expf(z) - 1.f);          // ELU
                f = 1.f / (1.f + __expf(-f));                   // sigmoid
                o = 1.f / (1.f + __expf(-o));                   // sigmoid
                c[r] = f * z + (1.f - f) * c[r];
                if (st)
                    out[(size_t)((sg * 16 + b) * 64 + hbase + r) * 128 + nidx] = o * c[r];
            }
        }

        // ---- write staged data to LDS ----
        if (do_stage) {
#pragma unroll
            for (int ss2 = 0; ss2 < 2; ++ss2) {
                int ss = ssp + ss2;
#pragma unroll
                for (int q = 0; q < 10; ++q) {
#pragma unroll
                    for (int e = 0; e < 4; ++e) {
                        int nl = q * 4 + e;
                        int byteoff = ((ss * 40 + nl) << 7) + ((scc * 2) ^ ((nl & 7) << 4));
                        *(short*)((char*)Xt + byteoff) = (short)f2bf(stg[ss2][q][e]);
                    }
                }
            }
        }
        __syncthreads();
    }

    // ---- C_last (Cseq[-1]) from chunk-1 blocks ----
    if (sc) {
#pragma unroll
        for (int r = 0; r < 4; ++r)
            out[(size_t)HOUT_ELEMS + (size_t)(b * 64 + hbase + r) * 128 + nidx] = c[r];
    }
}

extern "C" void kernel_launch(void* const* d_in, const int* in_sizes, int n_in,
                              void* d_out, int out_size, void* d_ws, size_t ws_size,
                              hipStream_t stream)
{
    (void)in_sizes; (void)n_in; (void)out_size; (void)ws_size;
    const float* X    = (const float*)d_in[0];   // (256,16,64,128) f32
    const float* hid  = (const float*)d_in[1];   // (16,64,128) f32
    const float* W    = (const float*)d_in[2];   // (192,64,1,9) f32
    const float* bias = (const float*)d_in[3];   // (192,) f32
    float* out = (float*)d_out;                  // Hout (256,16,64,128) ++ C_last (1,16,64,128)
    short* Wf  = (short*)d_ws;                   // 221,184 B of bf16 A-fragments

    prep_w_kernel<<<54, 256, 0, stream>>>(W, Wf);
    cqrn_main_kernel<<<256, 256, 0, stream>>>(X, hid, bias, Wf, out);
}

// Round 2
// 218.489 us; speedup vs baseline: 1.1809x; 1.1809x over previous
//
#include <hip/hip_runtime.h>
#include <hip/hip_bf16.h>

// CQRN fused kernel for MI355X (gfx950) — round 2
// S=256 B=16 C=64 N=128 H=64; conv(1x9,pad4) -> ELU/sig gates -> ForgetMult -> O*C
//
// Round-1 postmortem: 1 block/CU, 1 wave/SIMD, VGPR=256 -> latency-bound
// (MfmaUtil 18.6, VALUBusy 23.6, Occ 11.4).
// Round-2: 4 S-chunks (24-step warmup) -> 512 blocks = 2 blocks/CU = 2 waves/SIMD;
// s-batch 8->4, double-buffered 2x20KB X tile, ONE barrier per batch (dbuf),
// T14 load-early/write-late, VGPR target ~160 via __launch_bounds__(256,2).

typedef __attribute__((ext_vector_type(8))) short s8v;
typedef __attribute__((ext_vector_type(4))) float f4v;

#define HOUT_ELEMS (256*16*64*128)

__device__ __forceinline__ unsigned short f2bf(float x) {
    unsigned u = __float_as_uint(x);
    u += 0x7fffu + ((u >> 16) & 1u);   // round-to-nearest-even
    return (unsigned short)(u >> 16);
}

// ---------------- pre-pass: W -> A-fragment layout (bf16) ----------------
// Af[gt][ks][lane][j] : gt in [0,12) 16-row oc tiles; ks in [0,18) K-steps of 32
// oc = gt*16 + (lane&15); k = ks*32 + (lane>>4)*8 + j; tau = k>>6; c = k&63
__global__ void prep_w_kernel(const float* __restrict__ W, short* __restrict__ Wf) {
    int t = blockIdx.x * 256 + threadIdx.x;
    if (t >= 12 * 18 * 64) return;
    int lane = t & 63;
    int ks = (t >> 6) % 18;
    int gt = (t >> 6) / 18;
    int oc = gt * 16 + (lane & 15);
    s8v v;
#pragma unroll
    for (int j = 0; j < 8; ++j) {
        int k = ks * 32 + ((lane >> 4) << 3) + j;
        int tau = k >> 6;
        int cc = k & 63;
        v[j] = (short)f2bf(W[(oc * 64 + cc) * 9 + tau]);
    }
    *(s8v*)(Wf + (size_t)t * 8) = v;
}

// ---------------- main fused kernel ----------------
__global__ __launch_bounds__(256, 2)
void cqrn_main_kernel(const float* __restrict__ X, const float* __restrict__ hid,
                      const float* __restrict__ bias, const short* __restrict__ Wf,
                      float* __restrict__ out)
{
    // Double-buffered X tile: [buf][s(4)][nl(40)][c(64)] bf16, XOR-swizzled at
    // 16B granularity within each 128B row: byte_in_row = (2c) ^ ((nl&7)<<4).
    // 2 x 20,480 B = 40,960 B total -> 2 blocks/CU fit in 160 KiB LDS.
    __shared__ short Xt[2][4 * 40 * 64];

    const int tid  = threadIdx.x;
    const int lane = tid & 63;
    const int w    = tid >> 6;
    const int hs   = w >> 1;          // h-sub (16 rows)
    const int ns   = w & 1;           // n-sub (16 cols)

    const int bid = blockIdx.x;
    const int b   = bid & 15;
    const int h0  = ((bid >> 4) & 1) * 32;
    const int n0  = ((bid >> 5) & 3) * 32;
    const int sc  = (bid >> 7) & 3;

    const int s_begin = (sc == 0) ? 0 : (64 * sc - 24);   // 24-step warmup
    const int nb      = (sc == 0) ? 16 : 22;              // batches of 4 steps
    const int s_store = 64 * sc;                          // store [64sc, 64sc+64)

    // D fragment layout (16x16): col = lane&15, row = (lane>>4)*4 + reg
    const int drow  = (lane >> 4) << 2;
    const int dcol  = lane & 15;
    const int hbase = h0 + 16 * hs + drow;   // + r
    const int nidx  = n0 + 16 * ns + dcol;

    // biases folded into acc init
    f4v bzv, bfv, bov;
#pragma unroll
    for (int r = 0; r < 4; ++r) {
        bzv[r] = bias[hbase + r];
        bfv[r] = bias[64  + hbase + r];
        bov[r] = bias[128 + hbase + r];
    }

    // recurrence state
    float c[4];
#pragma unroll
    for (int r = 0; r < 4; ++r)
        c[r] = sc ? 0.f : hid[(size_t)(b * 64 + hbase + r) * 128 + nidx];

    // A-fragment base pointers (one per gate); tile index = g*4 + (h0>>4) + hs
    const short* Ap0 = Wf + (size_t)(((0 * 4 + (h0 >> 4) + hs) * 18) * 64 + lane) * 8;
    const short* Ap1 = Wf + (size_t)(((1 * 4 + (h0 >> 4) + hs) * 18) * 64 + lane) * 8;
    const short* Ap2 = Wf + (size_t)(((2 * 4 + (h0 >> 4) + hs) * 18) * 64 + lane) * 8;

    // staging mapping: lane -> channel c, wave -> s-slot
    const int scc = lane;

    // ---- prologue: stage batch 0 into buf 0 ----
    {
        const float* src = X + (size_t)(((s_begin + w) * 16 + b) * 64 + scc) * 128;
#pragma unroll
        for (int q = 0; q < 10; ++q) {
            int n = n0 - 4 + q * 4;
            f4v v = 0.f;
            if (n >= 0 && n < 128) v = *(const f4v*)(src + n);
#pragma unroll
            for (int e = 0; e < 4; ++e) {
                int nl = q * 4 + e;
                int byteoff = ((w * 40 + nl) << 7) + ((scc * 2) ^ ((nl & 7) << 4));
                *(short*)((char*)Xt[0] + byteoff) = (short)f2bf(v[e]);
            }
        }
    }
    __syncthreads();

    for (int bt = 0; bt < nb; ++bt) {
        const int sbase = s_begin + bt * 4;
        const int cur = bt & 1;
        const bool do_stage = (bt + 1 < nb);

        // ---- T14: issue next batch's global loads early ----
        f4v stg[10];
        if (do_stage) {
            const float* src = X + (size_t)(((sbase + 4 + w) * 16 + b) * 64 + scc) * 128;
#pragma unroll
            for (int q = 0; q < 10; ++q) {
                int n = n0 - 4 + q * 4;
                f4v v = 0.f;
                if (n >= 0 && n < 128) v = *(const f4v*)(src + n);
                stg[q] = v;
            }
        }

        // ---- GEMM on buf cur: K = 576 in 18 steps of 32 ----
        f4v acc[3][4];
#pragma unroll
        for (int s = 0; s < 4; ++s) {
            acc[0][s] = bzv; acc[1][s] = bfv; acc[2][s] = bov;
        }

        const char* XtCur = (const char*)Xt[cur];
#pragma unroll 2
        for (int ks = 0; ks < 18; ++ks) {
            s8v a0 = *(const s8v*)(Ap0 + (size_t)ks * 512);
            s8v a1 = *(const s8v*)(Ap1 + (size_t)ks * 512);
            s8v a2 = *(const s8v*)(Ap2 + (size_t)ks * 512);
            const int tau = ks >> 1;
            const int nl = dcol + 16 * ns + tau;
            const int cbyte = ((((ks & 1) << 6) + ((lane >> 4) << 4)) ^ ((nl & 7) << 4));
            const char* base = XtCur + (nl << 7) + cbyte;
#pragma unroll
            for (int s = 0; s < 4; ++s) {
                s8v bb = *(const s8v*)(base + s * 5120);
                acc[0][s] = __builtin_amdgcn_mfma_f32_16x16x32_bf16(a0, bb, acc[0][s], 0, 0, 0);
                acc[1][s] = __builtin_amdgcn_mfma_f32_16x16x32_bf16(a1, bb, acc[1][s], 0, 0, 0);
                acc[2][s] = __builtin_amdgcn_mfma_f32_16x16x32_bf16(a2, bb, acc[2][s], 0, 0, 0);
            }
        }

        // ---- write staged data to the OTHER buffer (no barrier needed) ----
        if (do_stage) {
            char* XtNxt = (char*)Xt[cur ^ 1];
#pragma unroll
            for (int q = 0; q < 10; ++q) {
#pragma unroll
                for (int e = 0; e < 4; ++e) {
                    int nl = q * 4 + e;
                    int byteoff = ((w * 40 + nl) << 7) + ((scc * 2) ^ ((nl & 7) << 4));
                    *(short*)(XtNxt + byteoff) = (short)f2bf(stg[q][e]);
                }
            }
        }

        // ---- activations + in-lane recurrence + Hout stores ----
#pragma unroll
        for (int s = 0; s < 4; ++s) {
            const int sg = sbase + s;
            const bool st = (sg >= s_store);
#pragma unroll
            for (int r = 0; r < 4; ++r) {
                float z = acc[0][s][r];
                float f = acc[1][s][r];
                float o = acc[2][s][r];
                z = (z > 0.f) ? z : (__expf(z) - 1.f);          // ELU
                f = 1.f / (1.f + __expf(-f));                   // sigmoid
                o = 1.f / (1.f + __expf(-o));                   // sigmoid
                c[r] = f * z + (1.f - f) * c[r];
                if (st)
                    out[(size_t)((sg * 16 + b) * 64 + hbase + r) * 128 + nidx] = o * c[r];
            }
        }

        // single barrier per batch: readers of cur done AND writers of nxt done
        __syncthreads();
    }

    // ---- C_last (Cseq[-1]) from the last S-chunk's blocks ----
    if (sc == 3) {
#pragma unroll
        for (int r = 0; r < 4; ++r)
            out[(size_t)HOUT_ELEMS + (size_t)(b * 64 + hbase + r) * 128 + nidx] = c[r];
    }
}

extern "C" void kernel_launch(void* const* d_in, const int* in_sizes, int n_in,
                              void* d_out, int out_size, void* d_ws, size_t ws_size,
                              hipStream_t stream)
{
    (void)in_sizes; (void)n_in; (void)out_size; (void)ws_size;
    const float* X    = (const float*)d_in[0];   // (256,16,64,128) f32
    const float* hid  = (const float*)d_in[1];   // (16,64,128) f32
    const float* W    = (const float*)d_in[2];   // (192,64,1,9) f32
    const float* bias = (const float*)d_in[3];   // (192,) f32
    float* out = (float*)d_out;                  // Hout ++ C_last
    short* Wf  = (short*)d_ws;                   // 221,184 B of bf16 A-fragments

    prep_w_kernel<<<54, 256, 0, stream>>>(W, Wf);
    cqrn_main_kernel<<<512, 256, 0, stream>>>(X, hid, bias, Wf, out);
}